// Round 1
// baseline (404.007 us; speedup 1.0000x reference)
//
#include <hip/hip_runtime.h>

#define B_  4
#define L_  4096
#define D_  2048
#define HD_ 128
#define M_  (B_*L_)   // 16384

typedef __attribute__((ext_vector_type(8))) short short8;
typedef __attribute__((ext_vector_type(4))) float f32x4;
typedef __attribute__((ext_vector_type(4))) unsigned short u16x4;
typedef unsigned short u16;

__device__ __forceinline__ u16 f2bf(float f){
  union { float f; unsigned u; } v; v.f = f;
  unsigned r = v.u + 0x7FFFu + ((v.u >> 16) & 1u);
  return (u16)(r >> 16);
}

__device__ __forceinline__ float bf2f(u16 h){
  union { unsigned u; float f; } v; v.u = ((unsigned)h) << 16;
  return v.f;
}

__device__ __forceinline__ float redmax16(float v){
  v = fmaxf(v, __shfl_xor(v, 1, 64));
  v = fmaxf(v, __shfl_xor(v, 2, 64));
  v = fmaxf(v, __shfl_xor(v, 4, 64));
  v = fmaxf(v, __shfl_xor(v, 8, 64));
  return v;
}
__device__ __forceinline__ float redsum16(float v){
  v += __shfl_xor(v, 1, 64);
  v += __shfl_xor(v, 2, 64);
  v += __shfl_xor(v, 4, 64);
  v += __shfl_xor(v, 8, 64);
  return v;
}

// ---------------- prep: cast + transpose weights to bf16 ----------------
// Wt_qkv[j][n][k] = Wj[k][n]   (j = 0:q 1:k 2:v), shape [3][128][2048] bf16
// Wt_o[n][k]      = Wo[k][n],  shape [2048][128] bf16
__global__ __launch_bounds__(256) void prep_kernel(
    const float* __restrict__ Wq, const float* __restrict__ Wk,
    const float* __restrict__ Wv, const float* __restrict__ Wo,
    u16* __restrict__ Wt_qkv, u16* __restrict__ Wt_o)
{
  int idx = blockIdx.x * 256 + threadIdx.x;       // grid covers exactly 1048576
  if (idx < 3*HD_*D_) {
    int j   = idx / (HD_*D_);
    int rem = idx - j*(HD_*D_);
    int n = rem >> 11;          // / 2048
    int k = rem & (D_-1);
    const float* W = (j==0) ? Wq : (j==1) ? Wk : Wv;
    Wt_qkv[idx] = f2bf(W[(size_t)k*HD_ + n]);
  } else {
    int i2 = idx - 3*HD_*D_;
    int n = i2 >> 7;            // / 128
    int k = i2 & (HD_-1);
    Wt_o[i2] = f2bf(Wo[(size_t)k*D_ + n]);
  }
}

// ---------------- QKV projection GEMM ----------------
// grid (3, 128): x = q/k/v selector, y = row block of 128
// block 256 threads = 4 waves, each wave a 64x64 quadrant, 16x16x32 bf16 MFMA
__global__ __launch_bounds__(256) void qkv_kernel(
    const float* __restrict__ x, const u16* __restrict__ Wt,
    const float* __restrict__ bq, const float* __restrict__ bk,
    const float* __restrict__ bv,
    u16* __restrict__ Q, u16* __restrict__ K, u16* __restrict__ V)
{
  const int cb = blockIdx.x;          // 0..2
  const int rb = blockIdx.y;          // 0..127
  const int tid  = threadIdx.x;
  const int lane = tid & 63, w = tid >> 6;
  const int wr = w >> 1, wc = w & 1;
  const int l15 = lane & 15, lhi = lane >> 4;

  __shared__ u16 Al[128][72];    // x tile, bf16, [row][k]
  __shared__ u16 Bl[128][72];    // W^T tile,    [n][k]

  const float* bias = (cb==0) ? bq : (cb==1) ? bk : bv;
  u16* Out          = (cb==0) ? Q  : (cb==1) ? K  : V;
  const u16* Wsrc   = Wt + (size_t)cb * HD_ * D_;
  const int row0 = rb * 128;

  f32x4 acc[4][4];
  f32x4 zero4 = {0.f, 0.f, 0.f, 0.f};
  for (int m=0;m<4;m++) for (int n=0;n<4;n++) acc[m][n] = zero4;

  for (int k0 = 0; k0 < D_; k0 += 64) {
    __syncthreads();
    // stage A: x[row0..row0+127][k0..k0+63] fp32 -> bf16
    #pragma unroll
    for (int i = 0; i < 8; i++) {
      int r = i*16 + (tid >> 4);
      int c = (tid & 15) * 4;
      float4 v4 = *reinterpret_cast<const float4*>(&x[(size_t)(row0+r)*D_ + k0 + c]);
      u16x4 b4;
      b4[0]=f2bf(v4.x); b4[1]=f2bf(v4.y); b4[2]=f2bf(v4.z); b4[3]=f2bf(v4.w);
      *reinterpret_cast<u16x4*>(&Al[r][c]) = b4;
    }
    // stage B: Wt[n][k0..k0+63] bf16
    #pragma unroll
    for (int i = 0; i < 4; i++) {
      int n = i*32 + (tid >> 3);
      int c = (tid & 7) * 8;
      short8 b8 = *reinterpret_cast<const short8*>(&Wsrc[(size_t)n*D_ + k0 + c]);
      *reinterpret_cast<short8*>(&Bl[n][c]) = b8;
    }
    __syncthreads();
    #pragma unroll
    for (int ks = 0; ks < 64; ks += 32) {
      short8 af[4], bfr[4];
      #pragma unroll
      for (int m=0;m<4;m++)
        af[m] = *reinterpret_cast<const short8*>(&Al[wr*64 + m*16 + l15][ks + (lhi<<3)]);
      #pragma unroll
      for (int n=0;n<4;n++)
        bfr[n] = *reinterpret_cast<const short8*>(&Bl[wc*64 + n*16 + l15][ks + (lhi<<3)]);
      #pragma unroll
      for (int m=0;m<4;m++)
        #pragma unroll
        for (int n=0;n<4;n++)
          acc[m][n] = __builtin_amdgcn_mfma_f32_16x16x32_bf16(af[m], bfr[n], acc[m][n], 0, 0, 0);
    }
  }
  // epilogue: bias + cast + store bf16
  #pragma unroll
  for (int n=0;n<4;n++) {
    int col = wc*64 + n*16 + l15;
    float b = bias[col];
    #pragma unroll
    for (int m=0;m<4;m++) {
      #pragma unroll
      for (int r=0;r<4;r++) {
        int row = row0 + wr*64 + m*16 + (lhi<<2) + r;
        Out[(size_t)row*HD_ + col] = f2bf(acc[m][n][r] + b);
      }
    }
  }
}

// ---------------- flash attention (causal) ----------------
// grid 256: b = blk>>6, q-tile = blk&63 (64 rows each)
// 4 waves, wave w owns q rows [q0+16w, q0+16w+16)
__global__ __launch_bounds__(256) void attn_kernel(
    const u16* __restrict__ Qg, const u16* __restrict__ Kg,
    const u16* __restrict__ Vg, u16* __restrict__ AO)
{
  const int b  = blockIdx.x >> 6;
  const int tq = blockIdx.x & 63;
  const int tid = threadIdx.x, lane = tid & 63, w = tid >> 6;
  const int l15 = lane & 15, lhi = lane >> 4;
  const int q0 = tq * 64;

  const u16* Qb = Qg + (size_t)b * L_ * HD_;
  const u16* Kb = Kg + (size_t)b * L_ * HD_;
  const u16* Vb = Vg + (size_t)b * L_ * HD_;

  __shared__ u16 Kl[64][136];    // [key][d]
  __shared__ u16 Vt[128][72];    // [d][key]
  __shared__ u16 Pl[4][16][72];  // per-wave P tile [qrow][key]

  // hoist Q fragments (A-operand: row = lane&15, k = 32*ks + 8*(lane>>4)+j)
  short8 qf[4];
  {
    int qrow = q0 + w*16 + l15;
    #pragma unroll
    for (int ks=0; ks<4; ks++)
      qf[ks] = *reinterpret_cast<const short8*>(&Qb[(size_t)qrow*HD_ + ks*32 + (lhi<<3)]);
  }

  f32x4 O[8];
  f32x4 zero4 = {0.f,0.f,0.f,0.f};
  #pragma unroll
  for (int of=0; of<8; of++) O[of] = zero4;
  float mrow[4] = {-__builtin_inff(), -__builtin_inff(), -__builtin_inff(), -__builtin_inff()};
  float lrow[4] = {0.f, 0.f, 0.f, 0.f};

  const float scale = 0.08838834764831845f;  // 1/sqrt(128)

  for (int kt = 0; kt <= tq; ++kt) {
    __syncthreads();
    // stage K (row-major) and V (transposed)
    #pragma unroll
    for (int i=0;i<4;i++) {
      int chunk = i*256 + tid;          // 1024 chunks of 8
      int r = chunk >> 4;               // 0..63
      int c = (chunk & 15) * 8;         // 0..120
      short8 k8 = *reinterpret_cast<const short8*>(&Kb[(size_t)(kt*64+r)*HD_ + c]);
      *reinterpret_cast<short8*>(&Kl[r][c]) = k8;
      short8 v8 = *reinterpret_cast<const short8*>(&Vb[(size_t)(kt*64+r)*HD_ + c]);
      u16* vv = reinterpret_cast<u16*>(&v8);
      #pragma unroll
      for (int j=0;j<8;j++) Vt[c+j][r] = vv[j];
    }
    __syncthreads();

    // S = Q K^T  (wave: 16 rows x 64 keys)
    f32x4 s[4];
    #pragma unroll
    for (int n=0;n<4;n++) s[n] = zero4;
    #pragma unroll
    for (int ks=0;ks<4;ks++) {
      #pragma unroll
      for (int n=0;n<4;n++) {
        short8 kb = *reinterpret_cast<const short8*>(&Kl[n*16 + l15][ks*32 + (lhi<<3)]);
        s[n] = __builtin_amdgcn_mfma_f32_16x16x32_bf16(qf[ks], kb, s[n], 0, 0, 0);
      }
    }
    // scale + causal mask (only binds on the diagonal tile)
    #pragma unroll
    for (int n=0;n<4;n++) {
      int key = kt*64 + n*16 + l15;
      #pragma unroll
      for (int r=0;r<4;r++) {
        int row = q0 + w*16 + (lhi<<2) + r;
        float v = s[n][r] * scale;
        s[n][r] = (key <= row) ? v : -__builtin_inff();
      }
    }
    // online softmax update
    #pragma unroll
    for (int r=0;r<4;r++) {
      float mx = fmaxf(fmaxf(s[0][r], s[1][r]), fmaxf(s[2][r], s[3][r]));
      mx = redmax16(mx);
      float mnew = fmaxf(mrow[r], mx);
      float alpha = __expf(mrow[r] - mnew);
      mrow[r] = mnew;
      float rsum = 0.f;
      #pragma unroll
      for (int n=0;n<4;n++) {
        float p = __expf(s[n][r] - mnew);
        s[n][r] = p;
        rsum += p;
      }
      rsum = redsum16(rsum);
      lrow[r] = lrow[r]*alpha + rsum;
      #pragma unroll
      for (int of=0; of<8; of++) O[of][r] *= alpha;
    }
    // P -> LDS (per-wave region), then PV
    #pragma unroll
    for (int n=0;n<4;n++)
      #pragma unroll
      for (int r=0;r<4;r++)
        Pl[w][(lhi<<2)+r][n*16 + l15] = f2bf(s[n][r]);
    __syncthreads();
    #pragma unroll
    for (int ks2=0; ks2<2; ks2++) {
      short8 pf = *reinterpret_cast<const short8*>(&Pl[w][l15][ks2*32 + (lhi<<3)]);
      #pragma unroll
      for (int of=0; of<8; of++) {
        short8 vf = *reinterpret_cast<const short8*>(&Vt[of*16 + l15][ks2*32 + (lhi<<3)]);
        O[of] = __builtin_amdgcn_mfma_f32_16x16x32_bf16(pf, vf, O[of], 0, 0, 0);
      }
    }
  }

  // finalize: O / l, store bf16
  #pragma unroll
  for (int r=0;r<4;r++) {
    float inv = 1.0f / lrow[r];
    int row = q0 + w*16 + (lhi<<2) + r;
    #pragma unroll
    for (int of=0; of<8; of++)
      AO[((size_t)b*L_ + row)*HD_ + of*16 + l15] = f2bf(O[of][r] * inv);
  }
}

// ---------------- output projection ----------------
// grid (16, 128): x = col block (128 wide), y = row block (128 rows). K = 128, single pass.
__global__ __launch_bounds__(256) void proj_kernel(
    const u16* __restrict__ AO, const u16* __restrict__ Wt_o,
    const float* __restrict__ bo, float* __restrict__ out)
{
  const int nb = blockIdx.x;   // 0..15
  const int rb = blockIdx.y;   // 0..127
  const int tid = threadIdx.x, lane = tid & 63, w = tid >> 6;
  const int wr = w >> 1, wc = w & 1;
  const int l15 = lane & 15, lhi = lane >> 4;
  const int row0 = rb * 128, n0 = nb * 128;

  __shared__ u16 Al[128][136];   // AO tile [row][k]
  __shared__ u16 Bl[128][136];   // Wo^T tile [n][k]

  #pragma unroll
  for (int i=0;i<8;i++) {
    int chunk = i*256 + tid;
    int r = chunk >> 4;
    int c = (chunk & 15) * 8;
    *reinterpret_cast<short8*>(&Al[r][c]) =
        *reinterpret_cast<const short8*>(&AO[(size_t)(row0+r)*HD_ + c]);
    *reinterpret_cast<short8*>(&Bl[r][c]) =
        *reinterpret_cast<const short8*>(&Wt_o[(size_t)(n0+r)*HD_ + c]);
  }
  __syncthreads();

  f32x4 acc[4][4];
  f32x4 zero4 = {0.f,0.f,0.f,0.f};
  for (int m=0;m<4;m++) for (int n=0;n<4;n++) acc[m][n] = zero4;

  #pragma unroll
  for (int ks=0; ks<128; ks+=32) {
    short8 af[4], bfr[4];
    #pragma unroll
    for (int m=0;m<4;m++)
      af[m] = *reinterpret_cast<const short8*>(&Al[wr*64 + m*16 + l15][ks + (lhi<<3)]);
    #pragma unroll
    for (int n=0;n<4;n++)
      bfr[n] = *reinterpret_cast<const short8*>(&Bl[wc*64 + n*16 + l15][ks + (lhi<<3)]);
    #pragma unroll
    for (int m=0;m<4;m++)
      #pragma unroll
      for (int n=0;n<4;n++)
        acc[m][n] = __builtin_amdgcn_mfma_f32_16x16x32_bf16(af[m], bfr[n], acc[m][n], 0, 0, 0);
  }

  #pragma unroll
  for (int n=0;n<4;n++) {
    int col = n0 + wc*64 + n*16 + l15;
    float b = bo[col];
    #pragma unroll
    for (int m=0;m<4;m++) {
      #pragma unroll
      for (int r=0;r<4;r++) {
        int row = row0 + wr*64 + m*16 + (lhi<<2) + r;
        out[(size_t)row*D_ + col] = acc[m][n][r] + b;
      }
    }
  }
}

// ---------------- launch ----------------
extern "C" void kernel_launch(void* const* d_in, const int* in_sizes, int n_in,
                              void* d_out, int out_size, void* d_ws, size_t ws_size,
                              hipStream_t stream) {
  const float* x  = (const float*)d_in[0];
  const float* Wq = (const float*)d_in[1];
  const float* bq = (const float*)d_in[2];
  const float* Wk = (const float*)d_in[3];
  const float* bk = (const float*)d_in[4];
  const float* Wv = (const float*)d_in[5];
  const float* bv = (const float*)d_in[6];
  const float* Wo = (const float*)d_in[7];
  const float* bo = (const float*)d_in[8];
  float* out = (float*)d_out;

  u16* ws      = (u16*)d_ws;
  u16* Wt_qkv  = ws;                          // 3*128*2048   = 786432
  u16* Wt_o    = Wt_qkv + 3*HD_*D_;           // 2048*128     = 262144
  u16* Q       = Wt_o   + (size_t)D_*HD_;     // 16384*128    = 2097152
  u16* K       = Q + (size_t)M_*HD_;
  u16* V       = K + (size_t)M_*HD_;
  u16* AO      = V + (size_t)M_*HD_;

  prep_kernel<<<4096, 256, 0, stream>>>(Wq, Wk, Wv, Wo, Wt_qkv, Wt_o);
  qkv_kernel<<<dim3(3, 128), 256, 0, stream>>>(x, Wt_qkv, bq, bk, bv, Q, K, V);
  attn_kernel<<<256, 256, 0, stream>>>(Q, K, V, AO);
  proj_kernel<<<dim3(16, 128), 256, 0, stream>>>(AO, Wt_o, bo, out);
}

// Round 2
// 291.679 us; speedup vs baseline: 1.3851x; 1.3851x over previous
//
#include <hip/hip_runtime.h>

#define B_  4
#define L_  4096
#define D_  2048
#define HD_ 128
#define M_  (B_*L_)   // 16384

typedef __attribute__((ext_vector_type(8))) short short8;
typedef __attribute__((ext_vector_type(4))) float f32x4;
typedef __attribute__((ext_vector_type(4))) unsigned short u16x4;
typedef unsigned short u16;

__device__ __forceinline__ u16 f2bf(float f){
  union { float f; unsigned u; } v; v.f = f;
  unsigned r = v.u + 0x7FFFu + ((v.u >> 16) & 1u);
  return (u16)(r >> 16);
}

__device__ __forceinline__ float redmax16(float v){
  v = fmaxf(v, __shfl_xor(v, 1, 64));
  v = fmaxf(v, __shfl_xor(v, 2, 64));
  v = fmaxf(v, __shfl_xor(v, 4, 64));
  v = fmaxf(v, __shfl_xor(v, 8, 64));
  return v;
}
__device__ __forceinline__ float redsum16(float v){
  v += __shfl_xor(v, 1, 64);
  v += __shfl_xor(v, 2, 64);
  v += __shfl_xor(v, 4, 64);
  v += __shfl_xor(v, 8, 64);
  return v;
}

// ---------------- prep: cast + transpose weights to bf16 ----------------
// Wt_qkv[col][k] = W{q,k,v}[k][col-within], col 0..383 (q|k|v stacked)
// Wt_o[n][k]     = Wo[k][n], shape [2048][128]
__global__ __launch_bounds__(256) void prep_kernel(
    const float* __restrict__ Wq, const float* __restrict__ Wk,
    const float* __restrict__ Wv, const float* __restrict__ Wo,
    u16* __restrict__ Wt_qkv, u16* __restrict__ Wt_o)
{
  int idx = blockIdx.x * 256 + threadIdx.x;       // grid covers exactly 1048576
  if (idx < 3*HD_*D_) {
    int j   = idx / (HD_*D_);
    int rem = idx - j*(HD_*D_);
    int n = rem >> 11;          // / 2048
    int k = rem & (D_-1);
    const float* W = (j==0) ? Wq : (j==1) ? Wk : Wv;
    Wt_qkv[idx] = f2bf(W[(size_t)k*HD_ + n]);
  } else {
    int i2 = idx - 3*HD_*D_;
    int n = i2 >> 7;            // / 128
    int k = i2 & (HD_-1);
    Wt_o[i2] = f2bf(Wo[(size_t)k*D_ + n]);
  }
}

// ---------------- fused QKV projection GEMM (N = 384, x read ONCE) -------
// grid 256 row-blocks of 64 rows; 512 threads = 8 waves (2 row x 4 col),
// wave tile = 32 rows x 96 cols. V written TRANSPOSED: Vt[b][d][l].
__global__ __launch_bounds__(512, 2) void qkv_kernel(
    const float* __restrict__ x, const u16* __restrict__ Wt,
    const float* __restrict__ bq, const float* __restrict__ bk,
    const float* __restrict__ bv,
    u16* __restrict__ Q, u16* __restrict__ K, u16* __restrict__ Vt)
{
  const int rb = blockIdx.x;          // 0..255
  const int tid  = threadIdx.x;
  const int lane = tid & 63, w = tid >> 6;
  const int wr = w >> 2, wc = w & 3;
  const int l15 = lane & 15, lhi = lane >> 4;
  const int row0 = rb * 64;

  __shared__ u16 Al[64][72];     // x tile bf16 [row][k]
  __shared__ u16 Bl[384][72];    // Wqkv^T tile [col][k]

  f32x4 acc[2][6];
  f32x4 zero4 = {0.f,0.f,0.f,0.f};
  #pragma unroll
  for (int m=0;m<2;m++)
    #pragma unroll
    for (int n=0;n<6;n++) acc[m][n] = zero4;

  for (int k0 = 0; k0 < D_; k0 += 64) {
    __syncthreads();
    // stage A: 64x64 fp32 -> bf16 (1024 float4 chunks / 512 thr)
    #pragma unroll
    for (int i=0;i<2;i++) {
      int idx = i*512 + tid;
      int r = idx >> 4, c = (idx & 15) * 4;
      float4 v4 = *reinterpret_cast<const float4*>(&x[(size_t)(row0+r)*D_ + k0 + c]);
      u16x4 b4;
      b4[0]=f2bf(v4.x); b4[1]=f2bf(v4.y); b4[2]=f2bf(v4.z); b4[3]=f2bf(v4.w);
      *reinterpret_cast<u16x4*>(&Al[r][c]) = b4;
    }
    // stage B: 384x64 bf16 (3072 short8 chunks / 512 thr)
    #pragma unroll
    for (int i=0;i<6;i++) {
      int idx = i*512 + tid;
      int r = idx >> 3, c = (idx & 7) * 8;
      *reinterpret_cast<short8*>(&Bl[r][c]) =
        *reinterpret_cast<const short8*>(&Wt[(size_t)r*D_ + k0 + c]);
    }
    __syncthreads();
    #pragma unroll
    for (int ks = 0; ks < 64; ks += 32) {
      short8 af[2], bfr[6];
      #pragma unroll
      for (int m=0;m<2;m++)
        af[m] = *reinterpret_cast<const short8*>(&Al[wr*32 + m*16 + l15][ks + (lhi<<3)]);
      #pragma unroll
      for (int n=0;n<6;n++)
        bfr[n] = *reinterpret_cast<const short8*>(&Bl[wc*96 + n*16 + l15][ks + (lhi<<3)]);
      #pragma unroll
      for (int m=0;m<2;m++)
        #pragma unroll
        for (int n=0;n<6;n++)
          acc[m][n] = __builtin_amdgcn_mfma_f32_16x16x32_bf16(af[m], bfr[n], acc[m][n], 0, 0, 0);
    }
  }
  // epilogue
  #pragma unroll
  for (int n=0;n<6;n++) {
    int col = wc*96 + n*16 + l15;
    int j = col >> 7;           // 0:Q 1:K 2:V (uniform per wave/n)
    int c = col & 127;
    float bias = (j==0) ? bq[c] : (j==1) ? bk[c] : bv[c];
    #pragma unroll
    for (int m=0;m<2;m++) {
      int rowb = row0 + wr*32 + m*16 + (lhi<<2);
      if (j < 2) {
        u16* Out = (j==0) ? Q : K;
        #pragma unroll
        for (int r=0;r<4;r++)
          Out[(size_t)(rowb+r)*HD_ + c] = f2bf(acc[m][n][r] + bias);
      } else {
        int bb = rowb >> 12;
        int l  = rowb & (L_-1);
        u16x4 v4;
        #pragma unroll
        for (int r=0;r<4;r++) v4[r] = f2bf(acc[m][n][r] + bias);
        *reinterpret_cast<u16x4*>(&Vt[(size_t)bb*HD_*L_ + (size_t)c*L_ + l]) = v4;
      }
    }
  }
}

// ---------------- flash attention (causal, key-split, barrier-free loop) --
// block = 16 q-rows, 4 waves; wave w handles key tiles kt ≡ w (mod 4) with
// private (m,l,O); merged at the end through LDS. K/Vt read straight from
// global (L2-resident). Grid 1024: batch pinned to XCD pair, work-descending.
__global__ __launch_bounds__(256, 3) void attn_kernel(
    const u16* __restrict__ Qg, const u16* __restrict__ Kg,
    const u16* __restrict__ Vtg, u16* __restrict__ AO)
{
  const int blk = blockIdx.x;
  const int xcd = blk & 7;
  const int sub = blk >> 3;                    // 0..127
  const int b   = xcd >> 1;                    // batch -> XCD pair
  const int strip = 255 - (2*sub + (xcd & 1)); // long strips dispatch first
  const int q0  = strip * 16;
  const int KT  = (strip >> 2) + 1;            // #64-key tiles needed

  const int tid = threadIdx.x, lane = tid & 63, w = tid >> 6;
  const int l15 = lane & 15, lhi = lane >> 4;

  const u16* Qb  = Qg  + (size_t)b * L_ * HD_;
  const u16* Kb  = Kg  + (size_t)b * L_ * HD_;
  const u16* Vtb = Vtg + (size_t)b * HD_ * L_;

  __shared__ u16 Pl[4][16][72];                       // per-wave P tile
  __shared__ __attribute__((aligned(16))) float Ol[4][16][132];
  __shared__ float Ml[4][16], Ll[4][16];

  // Q fragments (all 4 waves share the same 16 q-rows)
  short8 qf[4];
  #pragma unroll
  for (int ks=0; ks<4; ks++)
    qf[ks] = *reinterpret_cast<const short8*>(&Qb[(size_t)(q0 + l15)*HD_ + ks*32 + (lhi<<3)]);

  f32x4 O[8];
  f32x4 zero4 = {0.f,0.f,0.f,0.f};
  #pragma unroll
  for (int of=0; of<8; of++) O[of] = zero4;
  float mrow[4] = {-__builtin_inff(), -__builtin_inff(), -__builtin_inff(), -__builtin_inff()};
  float lrow[4] = {0.f, 0.f, 0.f, 0.f};
  const float scale = 0.08838834764831845f;  // 1/sqrt(128)

  for (int kt = w; kt < KT; kt += 4) {
    const u16* Kt = Kb + (size_t)kt*64*HD_;
    // S = Q K^T : 16 rows x 64 keys, K frags straight from global
    f32x4 s[4];
    #pragma unroll
    for (int n=0;n<4;n++) s[n] = zero4;
    #pragma unroll
    for (int ks=0;ks<4;ks++) {
      #pragma unroll
      for (int n=0;n<4;n++) {
        short8 kb = *reinterpret_cast<const short8*>(&Kt[(size_t)(n*16 + l15)*HD_ + ks*32 + (lhi<<3)]);
        s[n] = __builtin_amdgcn_mfma_f32_16x16x32_bf16(qf[ks], kb, s[n], 0, 0, 0);
      }
    }
    // scale (+ causal mask only on the diagonal tile)
    if (kt == KT-1) {
      #pragma unroll
      for (int n=0;n<4;n++) {
        int key = kt*64 + n*16 + l15;
        #pragma unroll
        for (int r=0;r<4;r++) {
          int row = q0 + (lhi<<2) + r;
          s[n][r] = (key <= row) ? s[n][r]*scale : -__builtin_inff();
        }
      }
    } else {
      #pragma unroll
      for (int n=0;n<4;n++)
        #pragma unroll
        for (int r=0;r<4;r++) s[n][r] *= scale;
    }
    // online softmax
    #pragma unroll
    for (int r=0;r<4;r++) {
      float mx = fmaxf(fmaxf(s[0][r], s[1][r]), fmaxf(s[2][r], s[3][r]));
      mx = redmax16(mx);
      float mnew = fmaxf(mrow[r], mx);
      float alpha = __expf(mrow[r] - mnew);
      mrow[r] = mnew;
      float rsum = 0.f;
      #pragma unroll
      for (int n=0;n<4;n++) {
        float p = __expf(s[n][r] - mnew);
        s[n][r] = p;
        rsum += p;
      }
      rsum = redsum16(rsum);
      lrow[r] = lrow[r]*alpha + rsum;
      #pragma unroll
      for (int of=0; of<8; of++) O[of][r] *= alpha;
    }
    // P -> per-wave LDS region (no barrier: same-wave write/read)
    #pragma unroll
    for (int n=0;n<4;n++)
      #pragma unroll
      for (int r=0;r<4;r++)
        Pl[w][(lhi<<2)+r][n*16 + l15] = f2bf(s[n][r]);
    // PV: Vt frags straight from global
    #pragma unroll
    for (int ks2=0; ks2<2; ks2++) {
      short8 pf = *reinterpret_cast<const short8*>(&Pl[w][l15][ks2*32 + (lhi<<3)]);
      const u16* Vk = Vtb + (size_t)kt*64 + ks2*32 + (lhi<<3);
      #pragma unroll
      for (int of=0; of<8; of++) {
        short8 vf = *reinterpret_cast<const short8*>(&Vk[(size_t)(of*16 + l15)*L_]);
        O[of] = __builtin_amdgcn_mfma_f32_16x16x32_bf16(pf, vf, O[of], 0, 0, 0);
      }
    }
  }

  // publish partials
  {
    int rb2 = lhi << 2;
    if (l15 == 0) {
      #pragma unroll
      for (int r=0;r<4;r++) { Ml[w][rb2+r] = mrow[r]; Ll[w][rb2+r] = lrow[r]; }
    }
    #pragma unroll
    for (int of=0; of<8; of++)
      #pragma unroll
      for (int r=0;r<4;r++)
        Ol[w][rb2+r][of*16 + l15] = O[of][r];
  }
  __syncthreads();

  // merge 4 key-split partials; thread -> (row, 8 cols)
  {
    int row = tid >> 4;
    int d0  = (tid & 15) * 8;
    float mw[4], lw[4];
    float M = -__builtin_inff();
    #pragma unroll
    for (int w2=0; w2<4; w2++) { mw[w2]=Ml[w2][row]; lw[w2]=Ll[w2][row]; M = fmaxf(M, mw[w2]); }
    float den = 0.f, cw[4];
    #pragma unroll
    for (int w2=0; w2<4; w2++) { float e = __expf(mw[w2]-M); cw[w2]=e; den += lw[w2]*e; }
    float inv = 1.0f/den;
    f32x4 o0 = zero4, o1 = zero4;
    #pragma unroll
    for (int w2=0; w2<4; w2++) {
      f32x4 p0 = *reinterpret_cast<const f32x4*>(&Ol[w2][row][d0]);
      f32x4 p1 = *reinterpret_cast<const f32x4*>(&Ol[w2][row][d0+4]);
      #pragma unroll
      for (int j=0;j<4;j++) { o0[j] += cw[w2]*p0[j]; o1[j] += cw[w2]*p1[j]; }
    }
    short8 st;
    #pragma unroll
    for (int j=0;j<4;j++) { st[j] = (short)f2bf(o0[j]*inv); st[j+4] = (short)f2bf(o1[j]*inv); }
    *reinterpret_cast<short8*>(&AO[((size_t)b*L_ + q0 + row)*HD_ + d0]) = st;
  }
}

// ---------------- output projection ----------------
__global__ __launch_bounds__(256) void proj_kernel(
    const u16* __restrict__ AO, const u16* __restrict__ Wt_o,
    const float* __restrict__ bo, float* __restrict__ out)
{
  const int nb = blockIdx.x;   // 0..15
  const int rb = blockIdx.y;   // 0..127
  const int tid = threadIdx.x, lane = tid & 63, w = tid >> 6;
  const int wr = w >> 1, wc = w & 1;
  const int l15 = lane & 15, lhi = lane >> 4;
  const int row0 = rb * 128, n0 = nb * 128;

  __shared__ u16 Al[128][136];
  __shared__ u16 Bl[128][136];

  #pragma unroll
  for (int i=0;i<8;i++) {
    int chunk = i*256 + tid;
    int r = chunk >> 4;
    int c = (chunk & 15) * 8;
    *reinterpret_cast<short8*>(&Al[r][c]) =
        *reinterpret_cast<const short8*>(&AO[(size_t)(row0+r)*HD_ + c]);
    *reinterpret_cast<short8*>(&Bl[r][c]) =
        *reinterpret_cast<const short8*>(&Wt_o[(size_t)(n0+r)*HD_ + c]);
  }
  __syncthreads();

  f32x4 acc[4][4];
  f32x4 zero4 = {0.f,0.f,0.f,0.f};
  for (int m=0;m<4;m++) for (int n=0;n<4;n++) acc[m][n] = zero4;

  #pragma unroll
  for (int ks=0; ks<128; ks+=32) {
    short8 af[4], bfr[4];
    #pragma unroll
    for (int m=0;m<4;m++)
      af[m] = *reinterpret_cast<const short8*>(&Al[wr*64 + m*16 + l15][ks + (lhi<<3)]);
    #pragma unroll
    for (int n=0;n<4;n++)
      bfr[n] = *reinterpret_cast<const short8*>(&Bl[wc*64 + n*16 + l15][ks + (lhi<<3)]);
    #pragma unroll
    for (int m=0;m<4;m++)
      #pragma unroll
      for (int n=0;n<4;n++)
        acc[m][n] = __builtin_amdgcn_mfma_f32_16x16x32_bf16(af[m], bfr[n], acc[m][n], 0, 0, 0);
  }

  #pragma unroll
  for (int n=0;n<4;n++) {
    int col = n0 + wc*64 + n*16 + l15;
    float b = bo[col];
    #pragma unroll
    for (int m=0;m<4;m++) {
      #pragma unroll
      for (int r=0;r<4;r++) {
        int row = row0 + wr*64 + m*16 + (lhi<<2) + r;
        out[(size_t)row*D_ + col] = acc[m][n][r] + b;
      }
    }
  }
}

// ---------------- launch ----------------
extern "C" void kernel_launch(void* const* d_in, const int* in_sizes, int n_in,
                              void* d_out, int out_size, void* d_ws, size_t ws_size,
                              hipStream_t stream) {
  const float* x  = (const float*)d_in[0];
  const float* Wq = (const float*)d_in[1];
  const float* bq = (const float*)d_in[2];
  const float* Wk = (const float*)d_in[3];
  const float* bk = (const float*)d_in[4];
  const float* Wv = (const float*)d_in[5];
  const float* bv = (const float*)d_in[6];
  const float* Wo = (const float*)d_in[7];
  const float* bo = (const float*)d_in[8];
  float* out = (float*)d_out;

  u16* ws      = (u16*)d_ws;
  u16* Wt_qkv  = ws;                          // [384][2048]
  u16* Wt_o    = Wt_qkv + 3*HD_*D_;           // [2048][128]
  u16* Q       = Wt_o   + (size_t)D_*HD_;     // [B*L][128]
  u16* K       = Q + (size_t)M_*HD_;          // [B*L][128]
  u16* Vt      = K + (size_t)M_*HD_;          // [B][128][4096]
  u16* AO      = Vt + (size_t)M_*HD_;         // [B*L][128]

  prep_kernel<<<4096, 256, 0, stream>>>(Wq, Wk, Wv, Wo, Wt_qkv, Wt_o);
  qkv_kernel<<<256, 512, 0, stream>>>(x, Wt_qkv, bq, bk, bv, Q, K, Vt);
  attn_kernel<<<1024, 256, 0, stream>>>(Q, K, Vt, AO);
  proj_kernel<<<dim3(16, 128), 256, 0, stream>>>(AO, Wt_o, bo, out);
}

// Round 3
// 237.714 us; speedup vs baseline: 1.6996x; 1.2270x over previous
//
#include <hip/hip_runtime.h>

#define B_  4
#define L_  4096
#define D_  2048
#define HD_ 128
#define M_  (B_*L_)   // 16384

typedef __attribute__((ext_vector_type(8))) short short8;
typedef __attribute__((ext_vector_type(4))) float f32x4;
typedef __attribute__((ext_vector_type(4))) unsigned short u16x4;
typedef unsigned short u16;

#define GLL16(g, l) __builtin_amdgcn_global_load_lds( \
    (const __attribute__((address_space(1))) void*)(g), \
    (__attribute__((address_space(3))) void*)(l), 16, 0, 0)

__device__ __forceinline__ u16 f2bf(float f){
  union { float f; unsigned u; } v; v.f = f;
  unsigned r = v.u + 0x7FFFu + ((v.u >> 16) & 1u);
  return (u16)(r >> 16);
}

__device__ __forceinline__ float redmax16(float v){
  v = fmaxf(v, __shfl_xor(v, 1, 64));
  v = fmaxf(v, __shfl_xor(v, 2, 64));
  v = fmaxf(v, __shfl_xor(v, 4, 64));
  v = fmaxf(v, __shfl_xor(v, 8, 64));
  return v;
}
__device__ __forceinline__ float redsum16(float v){
  v += __shfl_xor(v, 1, 64);
  v += __shfl_xor(v, 2, 64);
  v += __shfl_xor(v, 4, 64);
  v += __shfl_xor(v, 8, 64);
  return v;
}

// ---------------- prep: x fp32->bf16 cast + weight transposes ----------------
// blocks [0,16384): xb[i] = bf16(x[i]), 8 floats/thread
// blocks [16384,16640): 64x64 LDS-tiled transpose of Wq/Wk/Wv/Wo to bf16
//   Wt_qkv[mat*128 + n][k] = Wmat[k][n];  Wt_o[n][k] = Wo[k][n]
__global__ __launch_bounds__(256) void prep_kernel(
    const float* __restrict__ x,
    const float* __restrict__ Wq, const float* __restrict__ Wk,
    const float* __restrict__ Wv, const float* __restrict__ Wo,
    u16* __restrict__ xb, u16* __restrict__ Wt_qkv, u16* __restrict__ Wt_o)
{
  __shared__ float T[64][68];
  const int tid = threadIdx.x;
  if (blockIdx.x < 16384) {
    size_t base = ((size_t)blockIdx.x*256 + tid) * 8;
    float4 a = *reinterpret_cast<const float4*>(x + base);
    float4 b = *reinterpret_cast<const float4*>(x + base + 4);
    short8 o;
    o[0]=(short)f2bf(a.x); o[1]=(short)f2bf(a.y); o[2]=(short)f2bf(a.z); o[3]=(short)f2bf(a.w);
    o[4]=(short)f2bf(b.x); o[5]=(short)f2bf(b.y); o[6]=(short)f2bf(b.z); o[7]=(short)f2bf(b.w);
    *reinterpret_cast<short8*>(xb + base) = o;
  } else {
    int tb = blockIdx.x - 16384;        // 0..255
    int mat = tb >> 6, t = tb & 63;
    const float* src; u16* dst; int Rw, Cw, rt, ct;
    if (mat < 3) {
      src = (mat==0) ? Wq : (mat==1) ? Wk : Wv;
      dst = Wt_qkv + (size_t)mat*HD_*D_;
      Rw = D_; Cw = HD_; rt = t >> 1; ct = t & 1;
    } else {
      src = Wo; dst = Wt_o;
      Rw = HD_; Cw = D_; rt = t >> 5; ct = t & 31;
    }
    int r0 = rt*64, c0 = ct*64;
    #pragma unroll
    for (int i=0;i<4;i++){
      int fid = i*256 + tid;
      int row = fid >> 4, c4 = (fid & 15) * 4;
      float4 v = *reinterpret_cast<const float4*>(src + (size_t)(r0+row)*Cw + c0 + c4);
      *reinterpret_cast<float4*>(&T[row][c4]) = v;
    }
    __syncthreads();
    #pragma unroll
    for (int i=0;i<2;i++){
      int sid = i*256 + tid;
      int crow = sid >> 3, k8 = (sid & 7) * 8;
      short8 o;
      #pragma unroll
      for (int j=0;j<8;j++) o[j] = (short)f2bf(T[k8+j][crow]);
      *reinterpret_cast<short8*>(dst + (size_t)(c0+crow)*Rw + r0 + k8) = o;
    }
  }
}

// ---------------- fused QKV GEMM, m97 structure ----------------
// grid (128, 3): x = row-block (128 rows), y = cb (0:Q 1:K 2:V col-slice).
// 256 thr = 4 waves, wave = 64x64 quadrant (4x4 16x16x32 frags), BK=64.
// global_load_lds staging, XOR-swizzled source + swizzled frag reads.
__global__ __launch_bounds__(256, 3) void qkv_kernel(
    const u16* __restrict__ xb, const u16* __restrict__ Wt,
    const float* __restrict__ bq, const float* __restrict__ bk,
    const float* __restrict__ bv,
    u16* __restrict__ Q, u16* __restrict__ K, u16* __restrict__ Vt)
{
  const int rb = blockIdx.x;          // 0..127
  const int cb = blockIdx.y;          // 0..2
  const int tid  = threadIdx.x;
  const int lane = tid & 63, w = tid >> 6;
  const int wr = w >> 1, wc = w & 1;
  const int l15 = lane & 15, lhi = lane >> 4;
  const int row0 = rb * 128, col0 = cb * 128;

  __shared__ u16 Asm[128*64];
  __shared__ u16 Bsm[128*64];

  // staging: 16 x 1KB instrs per tile, 4 per wave; source pre-swizzled
  const u16* aSrc[4]; const u16* bSrc[4];
  u16* aDst[4]; u16* bDst[4];
  #pragma unroll
  for (int j=0;j<4;j++){
    int r = w*32 + j*8 + (lane >> 3);
    int c = ((lane & 7) ^ (r & 7)) << 3;
    aSrc[j] = xb + (size_t)(row0 + r)*D_ + c;
    bSrc[j] = Wt + (size_t)(col0 + r)*D_ + c;
    aDst[j] = Asm + (w*4 + j)*512;
    bDst[j] = Bsm + (w*4 + j)*512;
  }
  // frag LDS offsets (u16 units), swizzle-matched
  int offA[2][4], offB[2][4];
  #pragma unroll
  for (int ks=0;ks<2;ks++){
    #pragma unroll
    for (int m=0;m<4;m++){
      int rA = wr*64 + m*16 + l15;
      offA[ks][m] = rA*64 + ((((ks<<2)+lhi) ^ (rA&7)) << 3);
      int rB = wc*64 + m*16 + l15;
      offB[ks][m] = rB*64 + ((((ks<<2)+lhi) ^ (rB&7)) << 3);
    }
  }

  f32x4 acc[4][4];
  f32x4 zero4 = {0.f,0.f,0.f,0.f};
  #pragma unroll
  for (int m=0;m<4;m++)
    #pragma unroll
    for (int n=0;n<4;n++) acc[m][n] = zero4;

  for (int k0 = 0; k0 < D_; k0 += 64) {
    __syncthreads();
    #pragma unroll
    for (int j=0;j<4;j++){
      GLL16(aSrc[j], aDst[j]);
      GLL16(bSrc[j], bDst[j]);
      aSrc[j] += 64; bSrc[j] += 64;
    }
    __syncthreads();
    #pragma unroll
    for (int ks=0;ks<2;ks++){
      short8 fa[4], fb[4];
      #pragma unroll
      for (int m=0;m<4;m++) fa[m] = *reinterpret_cast<const short8*>(Asm + offA[ks][m]);
      #pragma unroll
      for (int n=0;n<4;n++) fb[n] = *reinterpret_cast<const short8*>(Bsm + offB[ks][n]);
      #pragma unroll
      for (int m=0;m<4;m++)
        #pragma unroll
        for (int n=0;n<4;n++)
          acc[m][n] = __builtin_amdgcn_mfma_f32_16x16x32_bf16(fa[m], fb[n], acc[m][n], 0, 0, 0);
    }
  }

  // epilogue
  if (cb < 2) {
    const float* bias = (cb==0) ? bq : bk;
    u16* Out = (cb==0) ? Q : K;
    #pragma unroll
    for (int n=0;n<4;n++){
      int col = wc*64 + n*16 + l15;
      float bi = bias[col];
      #pragma unroll
      for (int m=0;m<4;m++){
        int rowb = row0 + wr*64 + m*16 + (lhi<<2);
        #pragma unroll
        for (int r=0;r<4;r++)
          Out[(size_t)(rowb+r)*HD_ + col] = f2bf(acc[m][n][r] + bi);
      }
    }
  } else {
    #pragma unroll
    for (int n=0;n<4;n++){
      int d = wc*64 + n*16 + l15;
      float bi = bv[d];
      #pragma unroll
      for (int m=0;m<4;m++){
        int row = row0 + wr*64 + m*16 + (lhi<<2);
        int bb = row >> 12, l = row & (L_-1);
        u16x4 v4;
        #pragma unroll
        for (int r=0;r<4;r++) v4[r] = f2bf(acc[m][n][r] + bi);
        *reinterpret_cast<u16x4*>(Vt + (size_t)bb*HD_*L_ + (size_t)d*L_ + l) = v4;
      }
    }
  }
}

// ---------------- flash attention (causal, key-split, batched loads) ------
__global__ __launch_bounds__(256, 3) void attn_kernel(
    const u16* __restrict__ Qg, const u16* __restrict__ Kg,
    const u16* __restrict__ Vtg, u16* __restrict__ AO)
{
  const int blk = blockIdx.x;
  const int xcd = blk & 7;
  const int sub = blk >> 3;                    // 0..127
  const int b   = xcd >> 1;                    // batch -> XCD pair
  const int strip = 255 - (2*sub + (xcd & 1)); // long strips dispatch first
  const int q0  = strip * 16;
  const int KT  = (strip >> 2) + 1;            // #64-key tiles needed

  const int tid = threadIdx.x, lane = tid & 63, w = tid >> 6;
  const int l15 = lane & 15, lhi = lane >> 4;

  const u16* Qb  = Qg  + (size_t)b * L_ * HD_;
  const u16* Kb  = Kg  + (size_t)b * L_ * HD_;
  const u16* Vtb = Vtg + (size_t)b * HD_ * L_;

  __shared__ u16 Pl[4][16][72];
  __shared__ __attribute__((aligned(16))) float Ol[4][16][132];
  __shared__ float Ml[4][16], Ll[4][16];

  short8 qf[4];
  #pragma unroll
  for (int ks=0; ks<4; ks++)
    qf[ks] = *reinterpret_cast<const short8*>(&Qb[(size_t)(q0 + l15)*HD_ + ks*32 + (lhi<<3)]);

  f32x4 O[8];
  f32x4 zero4 = {0.f,0.f,0.f,0.f};
  #pragma unroll
  for (int of=0; of<8; of++) O[of] = zero4;
  float mrow[4] = {-__builtin_inff(), -__builtin_inff(), -__builtin_inff(), -__builtin_inff()};
  float lrow[4] = {0.f, 0.f, 0.f, 0.f};
  const float scale = 0.08838834764831845f;  // 1/sqrt(128)

  for (int kt = w; kt < KT; kt += 4) {
    const u16* Kt = Kb + (size_t)kt*64*HD_;
    // batched K-frag loads (all 16 in flight)
    short8 kb[4][4];
    #pragma unroll
    for (int ks=0;ks<4;ks++)
      #pragma unroll
      for (int n=0;n<4;n++)
        kb[ks][n] = *reinterpret_cast<const short8*>(
            &Kt[(size_t)(n*16 + l15)*HD_ + ks*32 + (lhi<<3)]);
    f32x4 s[4];
    #pragma unroll
    for (int n=0;n<4;n++) s[n] = zero4;
    __builtin_amdgcn_s_setprio(1);
    #pragma unroll
    for (int ks=0;ks<4;ks++)
      #pragma unroll
      for (int n=0;n<4;n++)
        s[n] = __builtin_amdgcn_mfma_f32_16x16x32_bf16(qf[ks], kb[ks][n], s[n], 0, 0, 0);
    __builtin_amdgcn_s_setprio(0);

    // issue all V-frag loads now; latency hides under softmax
    short8 vf[2][8];
    const u16* Vk = Vtb + (size_t)kt*64 + (lhi<<3);
    #pragma unroll
    for (int ks2=0;ks2<2;ks2++)
      #pragma unroll
      for (int of=0;of<8;of++)
        vf[ks2][of] = *reinterpret_cast<const short8*>(
            Vk + ks2*32 + (size_t)(of*16 + l15)*L_);

    // scale (+ causal mask on the diagonal tile only)
    if (kt == KT-1) {
      #pragma unroll
      for (int n=0;n<4;n++){
        int key = kt*64 + n*16 + l15;
        #pragma unroll
        for (int r=0;r<4;r++){
          int row = q0 + (lhi<<2) + r;
          s[n][r] = (key <= row) ? s[n][r]*scale : -__builtin_inff();
        }
      }
    } else {
      #pragma unroll
      for (int n=0;n<4;n++)
        #pragma unroll
        for (int r=0;r<4;r++) s[n][r] *= scale;
    }
    // online softmax
    #pragma unroll
    for (int r=0;r<4;r++){
      float mx = fmaxf(fmaxf(s[0][r], s[1][r]), fmaxf(s[2][r], s[3][r]));
      mx = redmax16(mx);
      float mnew = fmaxf(mrow[r], mx);
      float alpha = __expf(mrow[r] - mnew);
      mrow[r] = mnew;
      float rsum = 0.f;
      #pragma unroll
      for (int n=0;n<4;n++){
        float p = __expf(s[n][r] - mnew);
        s[n][r] = p;
        rsum += p;
      }
      rsum = redsum16(rsum);
      lrow[r] = lrow[r]*alpha + rsum;
      #pragma unroll
      for (int of=0; of<8; of++) O[of][r] *= alpha;
    }
    // P -> per-wave LDS (same-wave roundtrip, no barrier)
    #pragma unroll
    for (int n=0;n<4;n++)
      #pragma unroll
      for (int r=0;r<4;r++)
        Pl[w][(lhi<<2)+r][n*16 + l15] = f2bf(s[n][r]);
    __builtin_amdgcn_s_setprio(1);
    #pragma unroll
    for (int ks2=0; ks2<2; ks2++){
      short8 pf = *reinterpret_cast<const short8*>(&Pl[w][l15][ks2*32 + (lhi<<3)]);
      #pragma unroll
      for (int of=0; of<8; of++)
        O[of] = __builtin_amdgcn_mfma_f32_16x16x32_bf16(pf, vf[ks2][of], O[of], 0, 0, 0);
    }
    __builtin_amdgcn_s_setprio(0);
  }

  // publish partials
  {
    int rb2 = lhi << 2;
    if (l15 == 0) {
      #pragma unroll
      for (int r=0;r<4;r++){ Ml[w][rb2+r] = mrow[r]; Ll[w][rb2+r] = lrow[r]; }
    }
    #pragma unroll
    for (int of=0; of<8; of++)
      #pragma unroll
      for (int r=0;r<4;r++)
        Ol[w][rb2+r][of*16 + l15] = O[of][r];
  }
  __syncthreads();

  // merge 4 key-split partials
  {
    int row = tid >> 4;
    int d0  = (tid & 15) * 8;
    float mw[4], lw[4];
    float M = -__builtin_inff();
    #pragma unroll
    for (int w2=0; w2<4; w2++){ mw[w2]=Ml[w2][row]; lw[w2]=Ll[w2][row]; M = fmaxf(M, mw[w2]); }
    float den = 0.f, cw[4];
    #pragma unroll
    for (int w2=0; w2<4; w2++){ float e = __expf(mw[w2]-M); cw[w2]=e; den += lw[w2]*e; }
    float inv = 1.0f/den;
    f32x4 o0 = zero4, o1 = zero4;
    #pragma unroll
    for (int w2=0; w2<4; w2++){
      f32x4 p0 = *reinterpret_cast<const f32x4*>(&Ol[w2][row][d0]);
      f32x4 p1 = *reinterpret_cast<const f32x4*>(&Ol[w2][row][d0+4]);
      #pragma unroll
      for (int j=0;j<4;j++){ o0[j] += cw[w2]*p0[j]; o1[j] += cw[w2]*p1[j]; }
    }
    short8 st;
    #pragma unroll
    for (int j=0;j<4;j++){ st[j] = (short)f2bf(o0[j]*inv); st[j+4] = (short)f2bf(o1[j]*inv); }
    *reinterpret_cast<short8*>(&AO[((size_t)b*L_ + q0 + row)*HD_ + d0]) = st;
  }
}

// ---------------- output projection ----------------
__global__ __launch_bounds__(256) void proj_kernel(
    const u16* __restrict__ AO, const u16* __restrict__ Wt_o,
    const float* __restrict__ bo, float* __restrict__ out)
{
  const int nb = blockIdx.x;   // 0..15
  const int rb = blockIdx.y;   // 0..127
  const int tid = threadIdx.x, lane = tid & 63, w = tid >> 6;
  const int wr = w >> 1, wc = w & 1;
  const int l15 = lane & 15, lhi = lane >> 4;
  const int row0 = rb * 128, n0 = nb * 128;

  __shared__ u16 Al[128][136];
  __shared__ u16 Bl[128][136];

  #pragma unroll
  for (int i=0;i<8;i++){
    int chunk = i*256 + tid;
    int r = chunk >> 4;
    int c = (chunk & 15) * 8;
    *reinterpret_cast<short8*>(&Al[r][c]) =
        *reinterpret_cast<const short8*>(&AO[(size_t)(row0+r)*HD_ + c]);
    *reinterpret_cast<short8*>(&Bl[r][c]) =
        *reinterpret_cast<const short8*>(&Wt_o[(size_t)(n0+r)*HD_ + c]);
  }
  __syncthreads();

  f32x4 acc[4][4];
  f32x4 zero4 = {0.f,0.f,0.f,0.f};
  for (int m=0;m<4;m++) for (int n=0;n<4;n++) acc[m][n] = zero4;

  #pragma unroll
  for (int ks=0; ks<128; ks+=32){
    short8 fa[4], fb[4];
    #pragma unroll
    for (int m=0;m<4;m++)
      fa[m] = *reinterpret_cast<const short8*>(&Al[wr*64 + m*16 + l15][ks + (lhi<<3)]);
    #pragma unroll
    for (int n=0;n<4;n++)
      fb[n] = *reinterpret_cast<const short8*>(&Bl[wc*64 + n*16 + l15][ks + (lhi<<3)]);
    #pragma unroll
    for (int m=0;m<4;m++)
      #pragma unroll
      for (int n=0;n<4;n++)
        acc[m][n] = __builtin_amdgcn_mfma_f32_16x16x32_bf16(fa[m], fb[n], acc[m][n], 0, 0, 0);
  }

  #pragma unroll
  for (int n=0;n<4;n++){
    int col = n0 + wc*64 + n*16 + l15;
    float b = bo[col];
    #pragma unroll
    for (int m=0;m<4;m++){
      #pragma unroll
      for (int r=0;r<4;r++){
        int row = row0 + wr*64 + m*16 + (lhi<<2) + r;
        out[(size_t)row*D_ + col] = acc[m][n][r] + b;
      }
    }
  }
}

// ---------------- launch ----------------
extern "C" void kernel_launch(void* const* d_in, const int* in_sizes, int n_in,
                              void* d_out, int out_size, void* d_ws, size_t ws_size,
                              hipStream_t stream) {
  const float* x  = (const float*)d_in[0];
  const float* Wq = (const float*)d_in[1];
  const float* bq = (const float*)d_in[2];
  const float* Wk = (const float*)d_in[3];
  const float* bk = (const float*)d_in[4];
  const float* Wv = (const float*)d_in[5];
  const float* bv = (const float*)d_in[6];
  const float* Wo = (const float*)d_in[7];
  const float* bo = (const float*)d_in[8];
  float* out = (float*)d_out;

  u16* ws      = (u16*)d_ws;
  u16* xb      = ws;                            // [16384][2048] bf16 (67 MB)
  u16* Wt_qkv  = xb + (size_t)M_*D_;            // [384][2048]
  u16* Wt_o    = Wt_qkv + 3*HD_*D_;             // [2048][128]
  u16* Q       = Wt_o   + (size_t)D_*HD_;       // [B*L][128]
  u16* K       = Q + (size_t)M_*HD_;            // [B*L][128]
  u16* Vt      = K + (size_t)M_*HD_;            // [B][128][4096]
  u16* AO      = Vt + (size_t)M_*HD_;           // [B*L][128]

  prep_kernel<<<16640, 256, 0, stream>>>(x, Wq, Wk, Wv, Wo, xb, Wt_qkv, Wt_o);
  qkv_kernel<<<dim3(128, 3), 256, 0, stream>>>(xb, Wt_qkv, bq, bk, bv, Q, K, Vt);
  attn_kernel<<<1024, 256, 0, stream>>>(Q, K, Vt, AO);
  proj_kernel<<<dim3(16, 128), 256, 0, stream>>>(AO, Wt_o, bo, out);
}

// Round 4
// 237.396 us; speedup vs baseline: 1.7018x; 1.0013x over previous
//
#include <hip/hip_runtime.h>

#define B_  4
#define L_  4096
#define D_  2048
#define HD_ 128
#define M_  (B_*L_)   // 16384

typedef __attribute__((ext_vector_type(8))) short short8;
typedef __attribute__((ext_vector_type(4))) float f32x4;
typedef __attribute__((ext_vector_type(4))) unsigned short u16x4;
typedef unsigned short u16;

#define GLL16(g, l) __builtin_amdgcn_global_load_lds( \
    (const __attribute__((address_space(1))) void*)(g), \
    (__attribute__((address_space(3))) void*)(l), 16, 0, 0)

__device__ __forceinline__ u16 f2bf(float f){
  union { float f; unsigned u; } v; v.f = f;
  unsigned r = v.u + 0x7FFFu + ((v.u >> 16) & 1u);
  return (u16)(r >> 16);
}

__device__ __forceinline__ float redmax16(float v){
  v = fmaxf(v, __shfl_xor(v, 1, 64));
  v = fmaxf(v, __shfl_xor(v, 2, 64));
  v = fmaxf(v, __shfl_xor(v, 4, 64));
  v = fmaxf(v, __shfl_xor(v, 8, 64));
  return v;
}
__device__ __forceinline__ float redsum16(float v){
  v += __shfl_xor(v, 1, 64);
  v += __shfl_xor(v, 2, 64);
  v += __shfl_xor(v, 4, 64);
  v += __shfl_xor(v, 8, 64);
  return v;
}

// ---------------- prep: x fp32->bf16 cast + weight transposes ----------------
__global__ __launch_bounds__(256) void prep_kernel(
    const float* __restrict__ x,
    const float* __restrict__ Wq, const float* __restrict__ Wk,
    const float* __restrict__ Wv, const float* __restrict__ Wo,
    u16* __restrict__ xb, u16* __restrict__ Wt_qkv, u16* __restrict__ Wt_o)
{
  __shared__ float T[64][68];
  const int tid = threadIdx.x;
  if (blockIdx.x < 16384) {
    size_t base = ((size_t)blockIdx.x*256 + tid) * 8;
    float4 a = *reinterpret_cast<const float4*>(x + base);
    float4 b = *reinterpret_cast<const float4*>(x + base + 4);
    short8 o;
    o[0]=(short)f2bf(a.x); o[1]=(short)f2bf(a.y); o[2]=(short)f2bf(a.z); o[3]=(short)f2bf(a.w);
    o[4]=(short)f2bf(b.x); o[5]=(short)f2bf(b.y); o[6]=(short)f2bf(b.z); o[7]=(short)f2bf(b.w);
    *reinterpret_cast<short8*>(xb + base) = o;
  } else {
    int tb = blockIdx.x - 16384;        // 0..255
    int mat = tb >> 6, t = tb & 63;
    const float* src; u16* dst; int Rw, Cw, rt, ct;
    if (mat < 3) {
      src = (mat==0) ? Wq : (mat==1) ? Wk : Wv;
      dst = Wt_qkv + (size_t)mat*HD_*D_;
      Rw = D_; Cw = HD_; rt = t >> 1; ct = t & 1;
    } else {
      src = Wo; dst = Wt_o;
      Rw = HD_; Cw = D_; rt = t >> 5; ct = t & 31;
    }
    int r0 = rt*64, c0 = ct*64;
    #pragma unroll
    for (int i=0;i<4;i++){
      int fid = i*256 + tid;
      int row = fid >> 4, c4 = (fid & 15) * 4;
      float4 v = *reinterpret_cast<const float4*>(src + (size_t)(r0+row)*Cw + c0 + c4);
      *reinterpret_cast<float4*>(&T[row][c4]) = v;
    }
    __syncthreads();
    #pragma unroll
    for (int i=0;i<2;i++){
      int sid = i*256 + tid;
      int crow = sid >> 3, k8 = (sid & 7) * 8;
      short8 o;
      #pragma unroll
      for (int j=0;j<8;j++) o[j] = (short)f2bf(T[k8+j][crow]);
      *reinterpret_cast<short8*>(dst + (size_t)(c0+crow)*Rw + r0 + k8) = o;
    }
  }
}

// ---------------- fused QKV GEMM, m97 structure ----------------
// grid (3, 128): x = cb (Q/K/V), y = row-block -> the 3 cb-blocks of one rb
// are dispatch-adjacent, sharing the xb row-slice in L2.
__global__ __launch_bounds__(256, 3) void qkv_kernel(
    const u16* __restrict__ xb, const u16* __restrict__ Wt,
    const float* __restrict__ bq, const float* __restrict__ bk,
    const float* __restrict__ bv,
    u16* __restrict__ Q, u16* __restrict__ K, u16* __restrict__ Vt)
{
  const int cb = blockIdx.x;          // 0..2
  const int rb = blockIdx.y;          // 0..127
  const int tid  = threadIdx.x;
  const int lane = tid & 63, w = tid >> 6;
  const int wr = w >> 1, wc = w & 1;
  const int l15 = lane & 15, lhi = lane >> 4;
  const int row0 = rb * 128, col0 = cb * 128;

  __shared__ u16 Asm[128*64];
  __shared__ u16 Bsm[128*64];

  const u16* aSrc[4]; const u16* bSrc[4];
  u16* aDst[4]; u16* bDst[4];
  #pragma unroll
  for (int j=0;j<4;j++){
    int r = w*32 + j*8 + (lane >> 3);
    int c = ((lane & 7) ^ (r & 7)) << 3;
    aSrc[j] = xb + (size_t)(row0 + r)*D_ + c;
    bSrc[j] = Wt + (size_t)(col0 + r)*D_ + c;
    aDst[j] = Asm + (w*4 + j)*512;
    bDst[j] = Bsm + (w*4 + j)*512;
  }
  int offA[2][4], offB[2][4];
  #pragma unroll
  for (int ks=0;ks<2;ks++){
    #pragma unroll
    for (int m=0;m<4;m++){
      int rA = wr*64 + m*16 + l15;
      offA[ks][m] = rA*64 + ((((ks<<2)+lhi) ^ (rA&7)) << 3);
      int rB = wc*64 + m*16 + l15;
      offB[ks][m] = rB*64 + ((((ks<<2)+lhi) ^ (rB&7)) << 3);
    }
  }

  f32x4 acc[4][4];
  f32x4 zero4 = {0.f,0.f,0.f,0.f};
  #pragma unroll
  for (int m=0;m<4;m++)
    #pragma unroll
    for (int n=0;n<4;n++) acc[m][n] = zero4;

  for (int k0 = 0; k0 < D_; k0 += 64) {
    __syncthreads();
    #pragma unroll
    for (int j=0;j<4;j++){
      GLL16(aSrc[j], aDst[j]);
      GLL16(bSrc[j], bDst[j]);
      aSrc[j] += 64; bSrc[j] += 64;
    }
    __syncthreads();
    #pragma unroll
    for (int ks=0;ks<2;ks++){
      short8 fa[4], fb[4];
      #pragma unroll
      for (int m=0;m<4;m++) fa[m] = *reinterpret_cast<const short8*>(Asm + offA[ks][m]);
      #pragma unroll
      for (int n=0;n<4;n++) fb[n] = *reinterpret_cast<const short8*>(Bsm + offB[ks][n]);
      #pragma unroll
      for (int m=0;m<4;m++)
        #pragma unroll
        for (int n=0;n<4;n++)
          acc[m][n] = __builtin_amdgcn_mfma_f32_16x16x32_bf16(fa[m], fb[n], acc[m][n], 0, 0, 0);
    }
  }

  if (cb < 2) {
    const float* bias = (cb==0) ? bq : bk;
    u16* Out = (cb==0) ? Q : K;
    #pragma unroll
    for (int n=0;n<4;n++){
      int col = wc*64 + n*16 + l15;
      float bi = bias[col];
      #pragma unroll
      for (int m=0;m<4;m++){
        int rowb = row0 + wr*64 + m*16 + (lhi<<2);
        #pragma unroll
        for (int r=0;r<4;r++)
          Out[(size_t)(rowb+r)*HD_ + col] = f2bf(acc[m][n][r] + bi);
      }
    }
  } else {
    #pragma unroll
    for (int n=0;n<4;n++){
      int d = wc*64 + n*16 + l15;
      float bi = bv[d];
      #pragma unroll
      for (int m=0;m<4;m++){
        int row = row0 + wr*64 + m*16 + (lhi<<2);
        int bb = row >> 12, l = row & (L_-1);
        u16x4 v4;
        #pragma unroll
        for (int r=0;r<4;r++) v4[r] = f2bf(acc[m][n][r] + bi);
        *reinterpret_cast<u16x4*>(Vt + (size_t)bb*HD_*L_ + (size_t)d*L_ + l) = v4;
      }
    }
  }
}

// ---------------- flash attention (causal, LDS-staged K/V, dbuf) ----------
// 256 blocks (1/CU): batch -> XCD pair; block = 64 q-rows, 4 waves x 16 rows.
// K/V staged via global_load_lds (coalesced), XOR-swizzled both sides.
__global__ __launch_bounds__(256, 2) void attn_kernel(
    const u16* __restrict__ Qg, const u16* __restrict__ Kg,
    const u16* __restrict__ Vtg, u16* __restrict__ AO)
{
  const int blk = blockIdx.x;
  const int xcd = blk & 7;
  const int b   = xcd >> 1;                        // batch -> XCD pair
  const int strip = (blk >> 3) * 2 + (xcd & 1);    // 0..63
  const int q0 = strip * 64;
  const int KT = strip + 1;

  const int tid = threadIdx.x, lane = tid & 63, w = tid >> 6;
  const int l15 = lane & 15, lhi = lane >> 4;

  const u16* Qb  = Qg  + (size_t)b * L_ * HD_;
  const u16* Kb  = Kg  + (size_t)b * L_ * HD_;
  const u16* Vtb = Vtg + (size_t)b * HD_ * L_;

  __shared__ u16 Klds[2][64*128];    // [key][d], rows XOR-swizzled
  __shared__ u16 Vlds[2][128*64];    // [d][key], rows XOR-swizzled
  __shared__ u16 Pl[4][16][72];      // per-wave P tile

  // staging source offsets (pre-swizzled global addresses, rule 21)
  int kSrcOff[4], vSrcOff[4];        // u16 units, relative to tile base
  u16* kDst[4]; u16* vDst[4];        // wave-uniform LDS bases (buffer 0)
  #pragma unroll
  for (int j=0;j<4;j++){
    int kr = j*16 + (tid >> 4), kli = tid & 15;
    kSrcOff[j] = kr*HD_ + ((kli*8) ^ ((kr&7)*8));
    int vr = j*32 + (tid >> 3), vli = tid & 7;
    vSrcOff[j] = vr*L_ + ((vli*8) ^ ((vr&7)*8));
    kDst[j] = (u16*)&Klds[0][0] + j*2048 + w*512;
    vDst[j] = (u16*)&Vlds[0][0] + j*2048 + w*512;
  }

  // Q fragments
  short8 qf[4];
  #pragma unroll
  for (int ks=0; ks<4; ks++)
    qf[ks] = *reinterpret_cast<const short8*>(
        &Qb[(size_t)(q0 + w*16 + l15)*HD_ + ks*32 + (lhi<<3)]);

  // frag read offsets (u16 units, swizzle-matched), constant across kt
  int kFrag[4][4], vFrag[2][8];
  #pragma unroll
  for (int n=0;n<4;n++){
    int row = n*16 + l15;
    #pragma unroll
    for (int ks=0;ks<4;ks++)
      kFrag[ks][n] = row*128 + ((ks*32 + lhi*8) ^ ((row&7)*8));
  }
  #pragma unroll
  for (int of=0;of<8;of++){
    int row = of*16 + l15;
    #pragma unroll
    for (int ks2=0;ks2<2;ks2++)
      vFrag[ks2][of] = row*64 + ((ks2*32 + lhi*8) ^ ((row&7)*8));
  }

  f32x4 O[8];
  f32x4 zero4 = {0.f,0.f,0.f,0.f};
  #pragma unroll
  for (int of=0; of<8; of++) O[of] = zero4;
  float mrow[4] = {-__builtin_inff(), -__builtin_inff(), -__builtin_inff(), -__builtin_inff()};
  float lrow[4] = {0.f, 0.f, 0.f, 0.f};
  const float scale = 0.08838834764831845f;  // 1/sqrt(128)

  // prologue: stage tile 0 into buffer 0
  {
    const u16* kT = Kb;               // kt = 0
    const u16* vT = Vtb;
    #pragma unroll
    for (int j=0;j<4;j++){
      GLL16(kT + kSrcOff[j], kDst[j]);
      GLL16(vT + vSrcOff[j], vDst[j]);
    }
  }
  __syncthreads();   // drains vmcnt -> tile 0 ready

  for (int kt = 0; kt < KT; ++kt) {
    const int cur = kt & 1;
    // stage next tile into the other buffer (latency hides under compute)
    if (kt + 1 < KT) {
      const u16* kT = Kb  + (size_t)(kt+1)*64*HD_;
      const u16* vT = Vtb + (size_t)(kt+1)*64;
      const int nb = cur ^ 1;
      #pragma unroll
      for (int j=0;j<4;j++){
        GLL16(kT + kSrcOff[j], kDst[j] + nb*8192);
        GLL16(vT + vSrcOff[j], vDst[j] + nb*8192);
      }
    }
    const u16* Kc = &Klds[cur][0];
    const u16* Vc = &Vlds[cur][0];

    // S = Q K^T
    f32x4 s[4];
    #pragma unroll
    for (int n=0;n<4;n++) s[n] = zero4;
    __builtin_amdgcn_s_setprio(1);
    #pragma unroll
    for (int ks=0;ks<4;ks++)
      #pragma unroll
      for (int n=0;n<4;n++){
        short8 kbf = *reinterpret_cast<const short8*>(Kc + kFrag[ks][n]);
        s[n] = __builtin_amdgcn_mfma_f32_16x16x32_bf16(qf[ks], kbf, s[n], 0, 0, 0);
      }
    __builtin_amdgcn_s_setprio(0);

    // scale (+ causal mask on the diagonal tile only)
    if (kt == KT-1) {
      #pragma unroll
      for (int n=0;n<4;n++){
        int key = kt*64 + n*16 + l15;
        #pragma unroll
        for (int r=0;r<4;r++){
          int row = q0 + w*16 + (lhi<<2) + r;
          s[n][r] = (key <= row) ? s[n][r]*scale : -__builtin_inff();
        }
      }
    } else {
      #pragma unroll
      for (int n=0;n<4;n++)
        #pragma unroll
        for (int r=0;r<4;r++) s[n][r] *= scale;
    }
    // online softmax
    #pragma unroll
    for (int r=0;r<4;r++){
      float mx = fmaxf(fmaxf(s[0][r], s[1][r]), fmaxf(s[2][r], s[3][r]));
      mx = redmax16(mx);
      float mnew = fmaxf(mrow[r], mx);
      float alpha = __expf(mrow[r] - mnew);
      mrow[r] = mnew;
      float rsum = 0.f;
      #pragma unroll
      for (int n=0;n<4;n++){
        float p = __expf(s[n][r] - mnew);
        s[n][r] = p;
        rsum += p;
      }
      rsum = redsum16(rsum);
      lrow[r] = lrow[r]*alpha + rsum;
      #pragma unroll
      for (int of=0; of<8; of++) O[of][r] *= alpha;
    }
    // P -> per-wave LDS (same-wave roundtrip)
    #pragma unroll
    for (int n=0;n<4;n++)
      #pragma unroll
      for (int r=0;r<4;r++)
        Pl[w][(lhi<<2)+r][n*16 + l15] = f2bf(s[n][r]);
    // PV
    __builtin_amdgcn_s_setprio(1);
    #pragma unroll
    for (int ks2=0; ks2<2; ks2++){
      short8 pf = *reinterpret_cast<const short8*>(&Pl[w][l15][ks2*32 + (lhi<<3)]);
      #pragma unroll
      for (int of=0; of<8; of++){
        short8 vbf = *reinterpret_cast<const short8*>(Vc + vFrag[ks2][of]);
        O[of] = __builtin_amdgcn_mfma_f32_16x16x32_bf16(pf, vbf, O[of], 0, 0, 0);
      }
    }
    __builtin_amdgcn_s_setprio(0);

    __syncthreads();   // drains staged loads (vmcnt 0) + protects buffers
  }

  // epilogue: direct store (no merge needed)
  #pragma unroll
  for (int r=0;r<4;r++){
    float inv = 1.0f / lrow[r];
    int row = q0 + w*16 + (lhi<<2) + r;
    #pragma unroll
    for (int of=0; of<8; of++)
      AO[((size_t)b*L_ + row)*HD_ + of*16 + l15] = f2bf(O[of][r] * inv);
  }
}

// ---------------- output projection ----------------
__global__ __launch_bounds__(256) void proj_kernel(
    const u16* __restrict__ AO, const u16* __restrict__ Wt_o,
    const float* __restrict__ bo, float* __restrict__ out)
{
  const int nb = blockIdx.x;   // 0..15
  const int rb = blockIdx.y;   // 0..127
  const int tid = threadIdx.x, lane = tid & 63, w = tid >> 6;
  const int wr = w >> 1, wc = w & 1;
  const int l15 = lane & 15, lhi = lane >> 4;
  const int row0 = rb * 128, n0 = nb * 128;

  __shared__ u16 Al[128][136];
  __shared__ u16 Bl[128][136];

  #pragma unroll
  for (int i=0;i<8;i++){
    int chunk = i*256 + tid;
    int r = chunk >> 4;
    int c = (chunk & 15) * 8;
    *reinterpret_cast<short8*>(&Al[r][c]) =
        *reinterpret_cast<const short8*>(&AO[(size_t)(row0+r)*HD_ + c]);
    *reinterpret_cast<short8*>(&Bl[r][c]) =
        *reinterpret_cast<const short8*>(&Wt_o[(size_t)(n0+r)*HD_ + c]);
  }
  __syncthreads();

  f32x4 acc[4][4];
  f32x4 zero4 = {0.f,0.f,0.f,0.f};
  for (int m=0;m<4;m++) for (int n=0;n<4;n++) acc[m][n] = zero4;

  #pragma unroll
  for (int ks=0; ks<128; ks+=32){
    short8 fa[4], fb[4];
    #pragma unroll
    for (int m=0;m<4;m++)
      fa[m] = *reinterpret_cast<const short8*>(&Al[wr*64 + m*16 + l15][ks + (lhi<<3)]);
    #pragma unroll
    for (int n=0;n<4;n++)
      fb[n] = *reinterpret_cast<const short8*>(&Bl[wc*64 + n*16 + l15][ks + (lhi<<3)]);
    #pragma unroll
    for (int m=0;m<4;m++)
      #pragma unroll
      for (int n=0;n<4;n++)
        acc[m][n] = __builtin_amdgcn_mfma_f32_16x16x32_bf16(fa[m], fb[n], acc[m][n], 0, 0, 0);
  }

  #pragma unroll
  for (int n=0;n<4;n++){
    int col = n0 + wc*64 + n*16 + l15;
    float b = bo[col];
    #pragma unroll
    for (int m=0;m<4;m++){
      #pragma unroll
      for (int r=0;r<4;r++){
        int row = row0 + wr*64 + m*16 + (lhi<<2) + r;
        out[(size_t)row*D_ + col] = acc[m][n][r] + b;
      }
    }
  }
}

// ---------------- launch ----------------
extern "C" void kernel_launch(void* const* d_in, const int* in_sizes, int n_in,
                              void* d_out, int out_size, void* d_ws, size_t ws_size,
                              hipStream_t stream) {
  const float* x  = (const float*)d_in[0];
  const float* Wq = (const float*)d_in[1];
  const float* bq = (const float*)d_in[2];
  const float* Wk = (const float*)d_in[3];
  const float* bk = (const float*)d_in[4];
  const float* Wv = (const float*)d_in[5];
  const float* bv = (const float*)d_in[6];
  const float* Wo = (const float*)d_in[7];
  const float* bo = (const float*)d_in[8];
  float* out = (float*)d_out;

  u16* ws      = (u16*)d_ws;
  u16* xb      = ws;                            // [16384][2048] bf16 (67 MB)
  u16* Wt_qkv  = xb + (size_t)M_*D_;            // [384][2048]
  u16* Wt_o    = Wt_qkv + 3*HD_*D_;             // [2048][128]
  u16* Q       = Wt_o   + (size_t)D_*HD_;       // [B*L][128]
  u16* K       = Q + (size_t)M_*HD_;            // [B*L][128]
  u16* Vt      = K + (size_t)M_*HD_;            // [B][128][4096]
  u16* AO      = Vt + (size_t)M_*HD_;           // [B*L][128]

  prep_kernel<<<16640, 256, 0, stream>>>(x, Wq, Wk, Wv, Wo, xb, Wt_qkv, Wt_o);
  qkv_kernel<<<dim3(3, 128), 256, 0, stream>>>(xb, Wt_qkv, bq, bk, bv, Q, K, Vt);
  attn_kernel<<<256, 256, 0, stream>>>(Q, K, Vt, AO);
  proj_kernel<<<dim3(16, 128), 256, 0, stream>>>(AO, Wt_o, bo, out);
}